// Round 4
// baseline (417.889 us; speedup 1.0000x reference)
//
#include <hip/hip_runtime.h>
#include <hip/hip_bf16.h>
#include <math.h>

#define DD 64
#define BROWS 128          // rows per bucket
#define BSH 7              // log2(BROWS)
#define MAXB 512           // max buckets (single-block scan limit)
typedef unsigned long long u64;
typedef unsigned int u32;
typedef unsigned short u16;

// ---------------------------------------------------------------------------
// Linear: he = bf16( (x @ W^T) * artanh(||x||)/||x|| )  (exact telescoped
// logmap0(mobius_matvec(W,x,c=1))). One wave per row. Block 0 also zeroes
// the bucket counters (runs before bcount in stream order).
// ---------------------------------------------------------------------------
__global__ __launch_bounds__(256) void hgcn_linear(const float* __restrict__ x,
                                                   const float* __restrict__ W,
                                                   __hip_bfloat16* __restrict__ he,
                                                   int* __restrict__ bcnt,
                                                   int n) {
  if (blockIdx.x == 0) {
    for (int i = threadIdx.x; i < MAXB; i += 256) bcnt[i] = 0;
  }
  __shared__ float Wl[64][68];
  __shared__ float xs[4][64];
  const int tid = threadIdx.x;
  for (int i = tid; i < 64 * 64; i += 256) Wl[i >> 6][i & 63] = W[i];
  const int wave = tid >> 6, lane = tid & 63;
  const int row = blockIdx.x * 4 + wave;
  float xv = 0.f;
  if (row < n) xv = x[row * DD + lane];
  xs[wave][lane] = xv;
  __syncthreads();
  if (row >= n) return;

  float nx2 = xv * xv;
  #pragma unroll
  for (int m = 1; m < 64; m <<= 1) nx2 += __shfl_xor(nx2, m);
  const float nx = fmaxf(sqrtf(nx2), 1e-15f);
  const float z  = fminf(nx, 1.f - 1e-7f);
  const float s  = atanhf(z) / nx;

  const int j0 = (lane >> 3) & 7;
  float acc = 0.f;
  #pragma unroll
  for (int jj = 0; jj < 16; ++jj) {
    const int k = ((jj + j0) & 15) << 2;
    const float4 xk = *reinterpret_cast<const float4*>(&xs[wave][k]);
    const float4 wk = *reinterpret_cast<const float4*>(&Wl[lane][k]);
    acc = fmaf(xk.x, wk.x, acc);
    acc = fmaf(xk.y, wk.y, acc);
    acc = fmaf(xk.z, wk.z, acc);
    acc = fmaf(xk.w, wk.w, acc);
  }
  he[row * DD + lane] = __float2bfloat16(acc * s);
}

// ---------------------------------------------------------------------------
// Bucket histogram: per-block LDS hist -> few global atomics.
// ---------------------------------------------------------------------------
#define EPB 4096
__global__ __launch_bounds__(256) void hgcn_bcount(const int* __restrict__ ei,
                                                   int* __restrict__ bcnt,
                                                   int ne) {
  __shared__ int h[MAXB];
  const int t = threadIdx.x;
  h[t] = 0; h[t + 256] = 0;
  __syncthreads();
  const int e0 = blockIdx.x * EPB;
  const int e1 = min(e0 + EPB, ne);
  for (int e = e0 + t; e < e1; e += 256) atomicAdd(&h[ei[e] >> BSH], 1);
  __syncthreads();
  if (h[t])       atomicAdd(&bcnt[t], h[t]);
  if (h[t + 256]) atomicAdd(&bcnt[t + 256], h[t + 256]);
}

// ---------------------------------------------------------------------------
// Bucket exclusive scan (single block, 512 lanes); also inits cursors.
// ---------------------------------------------------------------------------
__global__ __launch_bounds__(512) void hgcn_bscan(const int* __restrict__ bcnt,
                                                  int* __restrict__ bbase,
                                                  int* __restrict__ bcur,
                                                  int nb, int ne) {
  __shared__ int s[MAXB];
  const int t = threadIdx.x;
  const int v = (t < nb) ? bcnt[t] : 0;
  s[t] = v;
  __syncthreads();
  for (int d = 1; d < 512; d <<= 1) {
    const int a = (t >= d) ? s[t - d] : 0;
    __syncthreads();
    s[t] += a;
    __syncthreads();
  }
  if (t < nb) {
    const int ex = s[t] - v;
    bbase[t] = ex;
    bcur[t] = ex;
  }
  if (t == 0) bbase[nb] = ne;
}

// ---------------------------------------------------------------------------
// Bin: stage packed edges (w:32 | rowLocal:8 | col:16) grouped by bucket.
// Per-block LDS hist -> contiguous run reservation -> near-coalesced writes.
// ---------------------------------------------------------------------------
#define BINB 1024
#define BINC 6144
__global__ __launch_bounds__(1024) void hgcn_bin(const int* __restrict__ ei,
                                                 const float* __restrict__ ew,
                                                 int* __restrict__ bcur,
                                                 u64* __restrict__ stage,
                                                 int ne) {
  __shared__ int h[MAXB], cur[MAXB], gp[MAXB];
  const int tid = threadIdx.x;
  if (tid < MAXB) { h[tid] = 0; cur[tid] = 0; }
  __syncthreads();
  const int eb = blockIdx.x * BINC;
  const int m = min(BINC, ne - eb);
  for (int i = tid; i < m; i += BINB) atomicAdd(&h[ei[eb + i] >> BSH], 1);
  __syncthreads();
  if (tid < MAXB) gp[tid] = h[tid] ? atomicAdd(&bcur[tid], h[tid]) : 0;
  __syncthreads();
  for (int i = tid; i < m; i += BINB) {
    const int r = ei[eb + i];
    const int c = ei[ne + eb + i];
    const float w = ew[eb + i];
    const int b = r >> BSH;
    const int pos = gp[b] + atomicAdd(&cur[b], 1);
    stage[pos] = ((u64)__float_as_uint(w) << 32) | ((u32)(r & (BROWS - 1)) << 16) | (u32)c;
  }
}

// ---------------------------------------------------------------------------
// Bucket aggregate + fused epilogue: one block per 128-row bucket.
// LDS fp32 accumulator sup[128][68] (pad-68 spreads ds_add_f32 banks).
// 8 lanes/edge -> 64 edges in flight per block; then per-row epilogue:
// out = proj(expmap0(relu(sup))).
// ---------------------------------------------------------------------------
__global__ __launch_bounds__(512) void hgcn_bagg(const u16* __restrict__ he,
                                                 const u64* __restrict__ stage,
                                                 const int* __restrict__ bbase,
                                                 float* __restrict__ out, int n) {
  __shared__ float sup[BROWS * 68];
  const int t = threadIdx.x;
  for (int i = t; i < BROWS * 68; i += 512) sup[i] = 0.f;
  __syncthreads();
  const int b = blockIdx.x;
  const int sbeg = bbase[b], send = bbase[b + 1];
  const int m = send - sbeg;
  const int g = t >> 3, l = t & 7;   // 64 groups x 8 lanes
  for (int i = g; i < m; i += 64) {
    const u64 p = stage[sbeg + i];
    const int   col = (int)(p & 0xffffu);
    const int   rl  = (int)((p >> 16) & 0xffu);
    const float w   = __uint_as_float((u32)(p >> 32));
    const uint4 q = reinterpret_cast<const uint4*>(he + ((size_t)col << 6))[l];
    float* srow = &sup[rl * 68 + l * 8];
    atomicAdd(&srow[0], w * __uint_as_float(q.x << 16));
    atomicAdd(&srow[1], w * __uint_as_float(q.x & 0xffff0000u));
    atomicAdd(&srow[2], w * __uint_as_float(q.y << 16));
    atomicAdd(&srow[3], w * __uint_as_float(q.y & 0xffff0000u));
    atomicAdd(&srow[4], w * __uint_as_float(q.z << 16));
    atomicAdd(&srow[5], w * __uint_as_float(q.z & 0xffff0000u));
    atomicAdd(&srow[6], w * __uint_as_float(q.w << 16));
    atomicAdd(&srow[7], w * __uint_as_float(q.w & 0xffff0000u));
  }
  __syncthreads();
  // epilogue: 8 waves, 16 rows each
  const int wave = t >> 6, lane = t & 63;
  for (int r = wave; r < BROWS; r += 8) {
    const int grow = (b << BSH) + r;
    if (grow >= n) break;
    const float a = fmaxf(sup[r * 68 + lane], 0.f);
    float p2 = a * a;
    #pragma unroll
    for (int mm = 1; mm < 64; mm <<= 1) p2 += __shfl_xor(p2, mm);
    const float nu = fmaxf(sqrtf(p2), 1e-15f);
    const float th = tanhf(nu);
    float scale = th / nu;
    const float maxn = 1.0f - 4e-3f;
    if (th > maxn) scale = maxn / nu;
    out[(size_t)grow * DD + lane] = a * scale;
  }
}

// ---------------------------------------------------------------------------
// Deep fallback (tiny ws): atomic scatter path, fp32.
// ---------------------------------------------------------------------------
__global__ __launch_bounds__(256) void hgcn_linf32(const float* __restrict__ x,
                                                   const float* __restrict__ W,
                                                   float* __restrict__ he, int n) {
  __shared__ float Wl[64][68];
  __shared__ float xs[4][64];
  const int tid = threadIdx.x;
  for (int i = tid; i < 64 * 64; i += 256) Wl[i >> 6][i & 63] = W[i];
  const int wave = tid >> 6, lane = tid & 63;
  const int row = blockIdx.x * 4 + wave;
  float xv = 0.f;
  if (row < n) xv = x[row * DD + lane];
  xs[wave][lane] = xv;
  __syncthreads();
  if (row >= n) return;
  float nx2 = xv * xv;
  #pragma unroll
  for (int m = 1; m < 64; m <<= 1) nx2 += __shfl_xor(nx2, m);
  const float nx = fmaxf(sqrtf(nx2), 1e-15f);
  const float s = atanhf(fminf(nx, 1.f - 1e-7f)) / nx;
  const int j0 = (lane >> 3) & 7;
  float acc = 0.f;
  #pragma unroll
  for (int jj = 0; jj < 16; ++jj) {
    const int k = ((jj + j0) & 15) << 2;
    const float4 xk = *reinterpret_cast<const float4*>(&xs[wave][k]);
    const float4 wk = *reinterpret_cast<const float4*>(&Wl[lane][k]);
    acc = fmaf(xk.x, wk.x, acc); acc = fmaf(xk.y, wk.y, acc);
    acc = fmaf(xk.z, wk.z, acc); acc = fmaf(xk.w, wk.w, acc);
  }
  he[row * DD + lane] = acc * s;
}

__global__ __launch_bounds__(256) void hgcn_zero(float* __restrict__ p, int n4) {
  const int i = blockIdx.x * 256 + threadIdx.x;
  if (i < n4) reinterpret_cast<float4*>(p)[i] = float4{0.f, 0.f, 0.f, 0.f};
}

__global__ __launch_bounds__(256) void hgcn_scatter(const float* __restrict__ he,
                                                    const int* __restrict__ ei,
                                                    const float* __restrict__ ew,
                                                    float* __restrict__ sup, int ne) {
  const int t = blockIdx.x * 256 + threadIdx.x;
  const int e = t >> 4, l = t & 15;
  if (e >= ne) return;
  const int row = ei[e];
  const int col = ei[ne + e];
  const float w = ew[e];
  const float4 v = *reinterpret_cast<const float4*>(he + (size_t)col * DD + l * 4);
  float* dst = sup + (size_t)row * DD + l * 4;
  unsafeAtomicAdd(dst + 0, w * v.x);
  unsafeAtomicAdd(dst + 1, w * v.y);
  unsafeAtomicAdd(dst + 2, w * v.z);
  unsafeAtomicAdd(dst + 3, w * v.w);
}

__global__ __launch_bounds__(256) void hgcn_final(const float* __restrict__ sup,
                                                  float* __restrict__ out, int n) {
  const int t = blockIdx.x * 256 + threadIdx.x;
  const int r = t >> 4, l = t & 15;
  if (r >= n) return;
  float4 v = *reinterpret_cast<const float4*>(sup + (size_t)r * DD + l * 4);
  v.x = fmaxf(v.x, 0.f); v.y = fmaxf(v.y, 0.f);
  v.z = fmaxf(v.z, 0.f); v.w = fmaxf(v.w, 0.f);
  float p = v.x*v.x + v.y*v.y + v.z*v.z + v.w*v.w;
  p += __shfl_xor(p, 1); p += __shfl_xor(p, 2);
  p += __shfl_xor(p, 4); p += __shfl_xor(p, 8);
  const float nu = fmaxf(sqrtf(p), 1e-15f);
  const float th = tanhf(nu);
  float scale = th / nu;
  const float maxn = 1.0f - 4e-3f;
  if (th > maxn) scale = maxn / nu;
  float4 o = {v.x*scale, v.y*scale, v.z*scale, v.w*scale};
  *reinterpret_cast<float4*>(out + (size_t)r * DD + l * 4) = o;
}

extern "C" void kernel_launch(void* const* d_in, const int* in_sizes, int n_in,
                              void* d_out, int out_size, void* d_ws, size_t ws_size,
                              hipStream_t stream) {
  const float* x  = (const float*)d_in[0];
  const float* W  = (const float*)d_in[1];
  const float* ew = (const float*)d_in[2];
  const int*   ei = (const int*)d_in[3];
  const int n  = in_sizes[0] / DD;   // 50000
  const int ne = in_sizes[2];        // 800000
  const int nb = (n + BROWS - 1) / BROWS;   // buckets (391)

  // ws layout
  size_t off_he    = 0;
  size_t off_stage = off_he + (((size_t)n * DD * 2 + 15) / 16) * 16;
  size_t off_bcnt  = off_stage + (size_t)ne * 8;
  size_t off_bbase = off_bcnt + MAXB * 4;
  size_t off_bcur  = off_bbase + (MAXB + 1) * 4;
  size_t need      = off_bcur + MAXB * 4 + 64;

  if (ws_size >= need && n <= 65536 && nb <= MAXB) {
    __hip_bfloat16* he = (__hip_bfloat16*)((char*)d_ws + off_he);
    u64* stage = (u64*)((char*)d_ws + off_stage);
    int* bcnt  = (int*)((char*)d_ws + off_bcnt);
    int* bbase = (int*)((char*)d_ws + off_bbase);
    int* bcur  = (int*)((char*)d_ws + off_bcur);
    float* out = (float*)d_out;

    hipLaunchKernelGGL(hgcn_linear, dim3((n + 3) / 4),            dim3(256),  0, stream, x, W, he, bcnt, n);
    hipLaunchKernelGGL(hgcn_bcount, dim3((ne + EPB - 1) / EPB),   dim3(256),  0, stream, ei, bcnt, ne);
    hipLaunchKernelGGL(hgcn_bscan,  dim3(1),                      dim3(512),  0, stream, bcnt, bbase, bcur, nb, ne);
    hipLaunchKernelGGL(hgcn_bin,    dim3((ne + BINC - 1) / BINC), dim3(BINB), 0, stream, ei, ew, bcur, stage, ne);
    hipLaunchKernelGGL(hgcn_bagg,   dim3(nb),                     dim3(512),  0, stream, (const u16*)he, stage, bbase, out, n);
  } else {
    float* he  = (float*)d_out;
    float* sup = (float*)d_ws;
    float* out = (float*)d_out;
    const int n4 = n * DD / 4;
    hipLaunchKernelGGL(hgcn_zero,    dim3((n4 + 255) / 256),       dim3(256), 0, stream, sup, n4);
    hipLaunchKernelGGL(hgcn_linf32,  dim3((n + 3) / 4),            dim3(256), 0, stream, x, W, he, n);
    hipLaunchKernelGGL(hgcn_scatter, dim3((ne * 16 + 255) / 256),  dim3(256), 0, stream, he, ei, ew, sup, ne);
    hipLaunchKernelGGL(hgcn_final,   dim3((n * 16 + 255) / 256),   dim3(256), 0, stream, sup, out, n);
  }
}

// Round 5
// 92.244 us; speedup vs baseline: 4.5303x; 4.5303x over previous
//
#include <hip/hip_runtime.h>
#include <hip/hip_bf16.h>
#include <math.h>

#define DD 64
#define BROWS 64           // rows per bucket
#define BSH 6              // log2(BROWS)
#define MAXB 1024          // max buckets (single-block scan limit)
#define CAP 2048           // bagg sort-chunk capacity (u64) = 16 KiB
typedef unsigned long long u64;
typedef unsigned int u32;
typedef unsigned short u16;

// ---------------------------------------------------------------------------
// Linear: he = bf16( (x @ W^T) * artanh(||x||)/||x|| )  (exact telescoped
// logmap0(mobius_matvec(W,x,c=1))). One wave per row. Block 0 also zeroes
// the bucket counters (stream order guarantees it lands before bcount).
// ---------------------------------------------------------------------------
__global__ __launch_bounds__(256) void hgcn_linear(const float* __restrict__ x,
                                                   const float* __restrict__ W,
                                                   __hip_bfloat16* __restrict__ he,
                                                   int* __restrict__ bcnt,
                                                   int n) {
  if (blockIdx.x == 0) {
    for (int i = threadIdx.x; i < MAXB; i += 256) bcnt[i] = 0;
  }
  __shared__ float Wl[64][68];
  __shared__ float xs[4][64];
  const int tid = threadIdx.x;
  for (int i = tid; i < 64 * 64; i += 256) Wl[i >> 6][i & 63] = W[i];
  const int wave = tid >> 6, lane = tid & 63;
  const int row = blockIdx.x * 4 + wave;
  float xv = 0.f;
  if (row < n) xv = x[row * DD + lane];
  xs[wave][lane] = xv;
  __syncthreads();
  if (row >= n) return;

  float nx2 = xv * xv;
  #pragma unroll
  for (int m = 1; m < 64; m <<= 1) nx2 += __shfl_xor(nx2, m);
  const float nx = fmaxf(sqrtf(nx2), 1e-15f);
  const float z  = fminf(nx, 1.f - 1e-7f);
  const float s  = atanhf(z) / nx;

  const int j0 = (lane >> 3) & 7;
  float acc = 0.f;
  #pragma unroll
  for (int jj = 0; jj < 16; ++jj) {
    const int k = ((jj + j0) & 15) << 2;
    const float4 xk = *reinterpret_cast<const float4*>(&xs[wave][k]);
    const float4 wk = *reinterpret_cast<const float4*>(&Wl[lane][k]);
    acc = fmaf(xk.x, wk.x, acc);
    acc = fmaf(xk.y, wk.y, acc);
    acc = fmaf(xk.z, wk.z, acc);
    acc = fmaf(xk.w, wk.w, acc);
  }
  he[row * DD + lane] = __float2bfloat16(acc * s);
}

// ---------------------------------------------------------------------------
// Bucket histogram: per-block LDS int hist -> few global atomics.
// ---------------------------------------------------------------------------
#define EPB 4096
__global__ __launch_bounds__(256) void hgcn_bcount(const int* __restrict__ ei,
                                                   int* __restrict__ bcnt,
                                                   int ne) {
  __shared__ int h[MAXB];
  const int t = threadIdx.x;
  #pragma unroll
  for (int k = 0; k < MAXB / 256; ++k) h[t + k * 256] = 0;
  __syncthreads();
  const int e0 = blockIdx.x * EPB;
  const int e1 = min(e0 + EPB, ne);
  for (int e = e0 + t; e < e1; e += 256) atomicAdd(&h[ei[e] >> BSH], 1);
  __syncthreads();
  #pragma unroll
  for (int k = 0; k < MAXB / 256; ++k)
    if (h[t + k * 256]) atomicAdd(&bcnt[t + k * 256], h[t + k * 256]);
}

// ---------------------------------------------------------------------------
// Bucket exclusive scan (single block, 1024 lanes); also inits cursors.
// ---------------------------------------------------------------------------
__global__ __launch_bounds__(1024) void hgcn_bscan(const int* __restrict__ bcnt,
                                                   int* __restrict__ bbase,
                                                   int* __restrict__ bcur,
                                                   int nb, int ne) {
  __shared__ int s[MAXB];
  const int t = threadIdx.x;
  const int v = (t < nb) ? bcnt[t] : 0;
  s[t] = v;
  __syncthreads();
  for (int d = 1; d < 1024; d <<= 1) {
    const int a = (t >= d) ? s[t - d] : 0;
    __syncthreads();
    s[t] += a;
    __syncthreads();
  }
  if (t < nb) {
    const int ex = s[t] - v;
    bbase[t] = ex;
    bcur[t] = ex;
  }
  if (t == 0) bbase[nb] = ne;
}

// ---------------------------------------------------------------------------
// Bin: stage packed edges (w:32 | rowLocal:16 | col:16) grouped by bucket.
// Per-block LDS hist -> contiguous run reservation -> near-coalesced writes.
// ---------------------------------------------------------------------------
#define BINB 1024
#define BINC 6144
__global__ __launch_bounds__(1024) void hgcn_bin(const int* __restrict__ ei,
                                                 const float* __restrict__ ew,
                                                 int* __restrict__ bcur,
                                                 u64* __restrict__ stage,
                                                 int ne) {
  __shared__ int h[MAXB], cur[MAXB], gp[MAXB];
  const int tid = threadIdx.x;
  h[tid] = 0; cur[tid] = 0;
  __syncthreads();
  const int eb = blockIdx.x * BINC;
  const int m = min(BINC, ne - eb);
  for (int i = tid; i < m; i += BINB) atomicAdd(&h[ei[eb + i] >> BSH], 1);
  __syncthreads();
  gp[tid] = h[tid] ? atomicAdd(&bcur[tid], h[tid]) : 0;
  __syncthreads();
  for (int i = tid; i < m; i += BINB) {
    const int r = ei[eb + i];
    const int c = ei[ne + eb + i];
    const float w = ew[eb + i];
    const int b = r >> BSH;
    const int pos = gp[b] + atomicAdd(&cur[b], 1);
    stage[pos] = ((u64)__float_as_uint(w) << 32) | ((u32)(r & (BROWS - 1)) << 16) | (u32)c;
  }
}

// ---------------------------------------------------------------------------
// Bucket aggregate + fused epilogue, NO fp atomics:
//  - chunked LDS counting sort by local row (int ds_add cursor + ds_write_b64,
//    the R3-regroup pattern, LDS-resident)
//  - each 8-lane group register-accumulates its 2 rows (16 VGPRs)
//  - fused relu/expmap0/proj epilogue, direct coalesced store.
// ---------------------------------------------------------------------------
__global__ __launch_bounds__(256) void hgcn_bagg(const u16* __restrict__ he,
                                                 const u64* __restrict__ stage,
                                                 const int* __restrict__ bbase,
                                                 float* __restrict__ out, int n) {
  __shared__ u64 ed[CAP];
  __shared__ int lh[BROWS + 1];   // exclusive row boundaries within chunk
  __shared__ int lcur[BROWS];     // counts, then cursors
  const int t = threadIdx.x;
  const int b = blockIdx.x;
  const int sbeg = bbase[b], send = bbase[b + 1];
  const int g = t >> 3, l = t & 7;          // 32 groups x 8 lanes
  const int r0 = 2 * g, r1 = 2 * g + 1;     // local rows owned by this group
  float a0[8] = {0.f, 0.f, 0.f, 0.f, 0.f, 0.f, 0.f, 0.f};
  float a1[8] = {0.f, 0.f, 0.f, 0.f, 0.f, 0.f, 0.f, 0.f};

  for (int cbeg = sbeg; cbeg < send; cbeg += CAP) {
    const int m = min(CAP, send - cbeg);
    if (t < BROWS) lcur[t] = 0;
    __syncthreads();
    for (int i = t; i < m; i += 256)
      atomicAdd(&lcur[(int)((stage[cbeg + i] >> 16) & (BROWS - 1))], 1);
    __syncthreads();
    if (t < 64) {                  // wave-scan 64 row counts -> exclusive
      const int v = lcur[t];
      int sc = v;
      #pragma unroll
      for (int d = 1; d < 64; d <<= 1) {
        const int u = __shfl_up(sc, d);
        if (t >= d) sc += u;
      }
      lh[t] = sc - v;
      lcur[t] = sc - v;
      if (t == 63) lh[64] = sc;
    }
    __syncthreads();
    for (int i = t; i < m; i += 256) {
      const u64 p = stage[cbeg + i];
      const int rl = (int)((p >> 16) & (BROWS - 1));
      const int pos = atomicAdd(&lcur[rl], 1);
      ed[pos] = p;
    }
    __syncthreads();
    // register-accumulate rows r0 and r1 (8 lanes split D=64 as 8x8)
    for (int j = lh[r0]; j < lh[r0 + 1]; ++j) {
      const u64 p = ed[j];
      const int col = (int)(p & 0xffffu);
      const float w = __uint_as_float((u32)(p >> 32));
      const uint4 q = reinterpret_cast<const uint4*>(he + ((size_t)col << 6))[l];
      a0[0] = fmaf(w, __uint_as_float(q.x << 16), a0[0]);
      a0[1] = fmaf(w, __uint_as_float(q.x & 0xffff0000u), a0[1]);
      a0[2] = fmaf(w, __uint_as_float(q.y << 16), a0[2]);
      a0[3] = fmaf(w, __uint_as_float(q.y & 0xffff0000u), a0[3]);
      a0[4] = fmaf(w, __uint_as_float(q.z << 16), a0[4]);
      a0[5] = fmaf(w, __uint_as_float(q.z & 0xffff0000u), a0[5]);
      a0[6] = fmaf(w, __uint_as_float(q.w << 16), a0[6]);
      a0[7] = fmaf(w, __uint_as_float(q.w & 0xffff0000u), a0[7]);
    }
    for (int j = lh[r1]; j < lh[r1 + 1]; ++j) {
      const u64 p = ed[j];
      const int col = (int)(p & 0xffffu);
      const float w = __uint_as_float((u32)(p >> 32));
      const uint4 q = reinterpret_cast<const uint4*>(he + ((size_t)col << 6))[l];
      a1[0] = fmaf(w, __uint_as_float(q.x << 16), a1[0]);
      a1[1] = fmaf(w, __uint_as_float(q.x & 0xffff0000u), a1[1]);
      a1[2] = fmaf(w, __uint_as_float(q.y << 16), a1[2]);
      a1[3] = fmaf(w, __uint_as_float(q.y & 0xffff0000u), a1[3]);
      a1[4] = fmaf(w, __uint_as_float(q.z << 16), a1[4]);
      a1[5] = fmaf(w, __uint_as_float(q.z & 0xffff0000u), a1[5]);
      a1[6] = fmaf(w, __uint_as_float(q.w << 16), a1[6]);
      a1[7] = fmaf(w, __uint_as_float(q.w & 0xffff0000u), a1[7]);
    }
    __syncthreads();   // before next chunk reuses ed
  }

  // epilogue: out = proj(expmap0(relu(acc)))  (8-lane group reduce)
  const float maxn = 1.0f - 4e-3f;
  {
    float ss = 0.f;
    #pragma unroll
    for (int k = 0; k < 8; ++k) { a0[k] = fmaxf(a0[k], 0.f); ss = fmaf(a0[k], a0[k], ss); }
    ss += __shfl_xor(ss, 1); ss += __shfl_xor(ss, 2); ss += __shfl_xor(ss, 4);
    const float nu = fmaxf(sqrtf(ss), 1e-15f);
    const float th = tanhf(nu);
    float scale = (th > maxn) ? (maxn / nu) : (th / nu);
    const int grow = (b << BSH) + r0;
    if (grow < n) {
      float4* op = reinterpret_cast<float4*>(out + (size_t)grow * DD + (size_t)l * 8);
      op[0] = float4{a0[0] * scale, a0[1] * scale, a0[2] * scale, a0[3] * scale};
      op[1] = float4{a0[4] * scale, a0[5] * scale, a0[6] * scale, a0[7] * scale};
    }
  }
  {
    float ss = 0.f;
    #pragma unroll
    for (int k = 0; k < 8; ++k) { a1[k] = fmaxf(a1[k], 0.f); ss = fmaf(a1[k], a1[k], ss); }
    ss += __shfl_xor(ss, 1); ss += __shfl_xor(ss, 2); ss += __shfl_xor(ss, 4);
    const float nu = fmaxf(sqrtf(ss), 1e-15f);
    const float th = tanhf(nu);
    float scale = (th > maxn) ? (maxn / nu) : (th / nu);
    const int grow = (b << BSH) + r1;
    if (grow < n) {
      float4* op = reinterpret_cast<float4*>(out + (size_t)grow * DD + (size_t)l * 8);
      op[0] = float4{a1[0] * scale, a1[1] * scale, a1[2] * scale, a1[3] * scale};
      op[1] = float4{a1[4] * scale, a1[5] * scale, a1[6] * scale, a1[7] * scale};
    }
  }
}

// ---------------------------------------------------------------------------
// Deep fallback (tiny ws): atomic scatter path, fp32 (round-1 structure).
// ---------------------------------------------------------------------------
__global__ __launch_bounds__(256) void hgcn_linf32(const float* __restrict__ x,
                                                   const float* __restrict__ W,
                                                   float* __restrict__ he, int n) {
  __shared__ float Wl[64][68];
  __shared__ float xs[4][64];
  const int tid = threadIdx.x;
  for (int i = tid; i < 64 * 64; i += 256) Wl[i >> 6][i & 63] = W[i];
  const int wave = tid >> 6, lane = tid & 63;
  const int row = blockIdx.x * 4 + wave;
  float xv = 0.f;
  if (row < n) xv = x[row * DD + lane];
  xs[wave][lane] = xv;
  __syncthreads();
  if (row >= n) return;
  float nx2 = xv * xv;
  #pragma unroll
  for (int m = 1; m < 64; m <<= 1) nx2 += __shfl_xor(nx2, m);
  const float nx = fmaxf(sqrtf(nx2), 1e-15f);
  const float s = atanhf(fminf(nx, 1.f - 1e-7f)) / nx;
  const int j0 = (lane >> 3) & 7;
  float acc = 0.f;
  #pragma unroll
  for (int jj = 0; jj < 16; ++jj) {
    const int k = ((jj + j0) & 15) << 2;
    const float4 xk = *reinterpret_cast<const float4*>(&xs[wave][k]);
    const float4 wk = *reinterpret_cast<const float4*>(&Wl[lane][k]);
    acc = fmaf(xk.x, wk.x, acc); acc = fmaf(xk.y, wk.y, acc);
    acc = fmaf(xk.z, wk.z, acc); acc = fmaf(xk.w, wk.w, acc);
  }
  he[row * DD + lane] = acc * s;
}

__global__ __launch_bounds__(256) void hgcn_zero(float* __restrict__ p, int n4) {
  const int i = blockIdx.x * 256 + threadIdx.x;
  if (i < n4) reinterpret_cast<float4*>(p)[i] = float4{0.f, 0.f, 0.f, 0.f};
}

__global__ __launch_bounds__(256) void hgcn_scatter(const float* __restrict__ he,
                                                    const int* __restrict__ ei,
                                                    const float* __restrict__ ew,
                                                    float* __restrict__ sup, int ne) {
  const int t = blockIdx.x * 256 + threadIdx.x;
  const int e = t >> 4, l = t & 15;
  if (e >= ne) return;
  const int row = ei[e];
  const int col = ei[ne + e];
  const float w = ew[e];
  const float4 v = *reinterpret_cast<const float4*>(he + (size_t)col * DD + l * 4);
  float* dst = sup + (size_t)row * DD + l * 4;
  unsafeAtomicAdd(dst + 0, w * v.x);
  unsafeAtomicAdd(dst + 1, w * v.y);
  unsafeAtomicAdd(dst + 2, w * v.z);
  unsafeAtomicAdd(dst + 3, w * v.w);
}

__global__ __launch_bounds__(256) void hgcn_final(const float* __restrict__ sup,
                                                  float* __restrict__ out, int n) {
  const int t = blockIdx.x * 256 + threadIdx.x;
  const int r = t >> 4, l = t & 15;
  if (r >= n) return;
  float4 v = *reinterpret_cast<const float4*>(sup + (size_t)r * DD + l * 4);
  v.x = fmaxf(v.x, 0.f); v.y = fmaxf(v.y, 0.f);
  v.z = fmaxf(v.z, 0.f); v.w = fmaxf(v.w, 0.f);
  float p = v.x*v.x + v.y*v.y + v.z*v.z + v.w*v.w;
  p += __shfl_xor(p, 1); p += __shfl_xor(p, 2);
  p += __shfl_xor(p, 4); p += __shfl_xor(p, 8);
  const float nu = fmaxf(sqrtf(p), 1e-15f);
  const float th = tanhf(nu);
  float scale = th / nu;
  const float maxn = 1.0f - 4e-3f;
  if (th > maxn) scale = maxn / nu;
  float4 o = {v.x*scale, v.y*scale, v.z*scale, v.w*scale};
  *reinterpret_cast<float4*>(out + (size_t)r * DD + l * 4) = o;
}

extern "C" void kernel_launch(void* const* d_in, const int* in_sizes, int n_in,
                              void* d_out, int out_size, void* d_ws, size_t ws_size,
                              hipStream_t stream) {
  const float* x  = (const float*)d_in[0];
  const float* W  = (const float*)d_in[1];
  const float* ew = (const float*)d_in[2];
  const int*   ei = (const int*)d_in[3];
  const int n  = in_sizes[0] / DD;          // 50000
  const int ne = in_sizes[2];               // 800000
  const int nb = (n + BROWS - 1) / BROWS;   // buckets (782)

  // ws layout
  size_t off_he    = 0;
  size_t off_stage = off_he + (((size_t)n * DD * 2 + 15) / 16) * 16;
  size_t off_bcnt  = off_stage + (size_t)ne * 8;
  size_t off_bbase = off_bcnt + MAXB * 4;
  size_t off_bcur  = off_bbase + (MAXB + 1) * 4;
  size_t need      = off_bcur + MAXB * 4 + 64;

  if (ws_size >= need && n <= 65536 && nb <= MAXB) {
    __hip_bfloat16* he = (__hip_bfloat16*)((char*)d_ws + off_he);
    u64* stage = (u64*)((char*)d_ws + off_stage);
    int* bcnt  = (int*)((char*)d_ws + off_bcnt);
    int* bbase = (int*)((char*)d_ws + off_bbase);
    int* bcur  = (int*)((char*)d_ws + off_bcur);
    float* out = (float*)d_out;

    hipLaunchKernelGGL(hgcn_linear, dim3((n + 3) / 4),            dim3(256),  0, stream, x, W, he, bcnt, n);
    hipLaunchKernelGGL(hgcn_bcount, dim3((ne + EPB - 1) / EPB),   dim3(256),  0, stream, ei, bcnt, ne);
    hipLaunchKernelGGL(hgcn_bscan,  dim3(1),                      dim3(1024), 0, stream, bcnt, bbase, bcur, nb, ne);
    hipLaunchKernelGGL(hgcn_bin,    dim3((ne + BINC - 1) / BINC), dim3(BINB), 0, stream, ei, ew, bcur, stage, ne);
    hipLaunchKernelGGL(hgcn_bagg,   dim3(nb),                     dim3(256),  0, stream, (const u16*)he, stage, bbase, out, n);
  } else {
    float* he  = (float*)d_out;
    float* sup = (float*)d_ws;
    float* out = (float*)d_out;
    const int n4 = n * DD / 4;
    hipLaunchKernelGGL(hgcn_zero,    dim3((n4 + 255) / 256),       dim3(256), 0, stream, sup, n4);
    hipLaunchKernelGGL(hgcn_linf32,  dim3((n + 3) / 4),            dim3(256), 0, stream, x, W, he, n);
    hipLaunchKernelGGL(hgcn_scatter, dim3((ne * 16 + 255) / 256),  dim3(256), 0, stream, he, ei, ew, sup, ne);
    hipLaunchKernelGGL(hgcn_final,   dim3((n * 16 + 255) / 256),   dim3(256), 0, stream, sup, out, n);
  }
}